// Round 11
// baseline (208.258 us; speedup 1.0000x reference)
//
#include <hip/hip_runtime.h>
#include <stdint.h>

// Problem constants (from reference)
#define N_NODES 16384
#define E_EDGES 524288
#define F_INF   128      // node feature dim
#define H_DIM   256      // hidden dim
#define A_DIM   64       // action size
#define BCAP    128      // bucket capacity per source (Poisson(32) tail ~1e-40)

// ---------------- ws layout ----------------
// [0, 64KB)     : cnt uint32[16384]    (zeroed each launch)
// [64KB, +1KB)  : g_accum float[256]   (zeroed each launch)
// [80KB, +64KB) : W_bf uint16[256][128]
// [160KB, +4MB) : bucket uint16[N][BCAP]
// [then, +4MB)  : t_bf uint16[N][128]
#define CNT_OFF    0
#define GACC_OFF   (64 * 1024)
#define WBF_OFF    (80 * 1024)
#define BUCKET_OFF (160 * 1024)
#define TBF_OFF    (BUCKET_OFF + (size_t)N_NODES * BCAP * 2)

typedef __attribute__((ext_vector_type(8))) short bf16x8;
typedef __attribute__((ext_vector_type(4))) float f32x4;

// round-to-nearest-even fp32 -> bf16 (bit pattern in low 16)
__device__ __forceinline__ uint32_t f32_to_bf16(float f) {
    uint32_t u = __float_as_uint(f);
    return (u + 0x7FFFu + ((u >> 16) & 1u)) >> 16;
}

// ---------------------------------------------------------------
// K0: W_gnn fp32 -> bf16 (32768 elems, one-shot)
// ---------------------------------------------------------------
__global__ __launch_bounds__(256) void k_wconv(const float* __restrict__ Wg,
                                               uint16_t* __restrict__ Wbf) {
    int i = blockIdx.x * 256 + threadIdx.x;
    Wbf[i] = (uint16_t)f32_to_bf16(Wg[i]);
}

// ---------------------------------------------------------------
// K1: bucketed adjacency-list build. slot=atomicAdd(cnt[s]) gives
// position and final count. Counters 64KB (L2-hot), buckets 4MB.
// ---------------------------------------------------------------
__global__ __launch_bounds__(256) void k_fill(const int* __restrict__ ei,
                                              uint32_t* __restrict__ cnt,
                                              uint16_t* __restrict__ bucket) {
    int e = blockIdx.x * 256 + threadIdx.x;
    int s = ei[e];              // edge_index[0][e]
    int d = ei[E_EDGES + e];    // edge_index[1][e]
    uint32_t slot = atomicAdd(&cnt[s], 1u);
    if (slot < BCAP) bucket[(size_t)s * BCAP + slot] = (uint16_t)d;
}

// ---------------------------------------------------------------
// K2: one wave per node. LDS-bitmap set-dedup, ballot compaction,
// batched MLP=8 float2 gathers. Epilogue now writes t as PACKED
// BF16 (2 elems/lane -> one u32 store, coalesced): halves t
// traffic and feeds the MFMA gemm directly.
// ---------------------------------------------------------------
__global__ __launch_bounds__(256) void k_gather(const float* __restrict__ X,
                                                const uint32_t* __restrict__ cnt,
                                                const uint16_t* __restrict__ bucket,
                                                uint32_t* __restrict__ tbf) {
    __shared__ uint32_t bmp[4][512];    // 16384 bits per wave
    __shared__ uint16_t q[4][BCAP];
    int wid  = threadIdx.x >> 6;
    int lane = threadIdx.x & 63;
    int n    = blockIdx.x * 4 + wid;
    uint32_t* mybm = bmp[wid];
    uint16_t* myq  = q[wid];
    const float2* X2 = (const float2*)X;

#pragma unroll
    for (int i = 0; i < 8; ++i) mybm[lane + i * 64] = 0u;

    int m = (int)cnt[n];
    if (m > BCAP) m = BCAP;
    const uint16_t* list = bucket + (size_t)n * BCAP;

    int qn = 0;
    for (int base = 0; base < m; base += 64) {
        int idx = base + lane;
        int d = 0;
        bool keep = false;
        if (idx < m) {
            d = list[idx];
            uint32_t bit = 1u << (d & 31);
            uint32_t old = atomicOr(&mybm[d >> 5], bit);
            keep = !(old & bit);
        }
        unsigned long long mask = __ballot(keep);
        int pos = qn + __popcll(mask & ((1ull << lane) - 1ull));
        if (keep) myq[pos] = (uint16_t)d;
        qn += __popcll(mask);
    }

    float2 a = X2[(size_t)n * 64 + lane];       // identity term
    int cdeg = 1 + qn;

    const uint64_t* q8 = (const uint64_t*)myq;
    int i = 0;
    for (; i + 8 <= qn; i += 8) {
        uint64_t p0 = q8[(i >> 2)];
        uint64_t p1 = q8[(i >> 2) + 1];
        int d0 = (int)(p0 & 0xFFFF), d1 = (int)((p0 >> 16) & 0xFFFF);
        int d2 = (int)((p0 >> 32) & 0xFFFF), d3 = (int)(p0 >> 48);
        int d4 = (int)(p1 & 0xFFFF), d5 = (int)((p1 >> 16) & 0xFFFF);
        int d6 = (int)((p1 >> 32) & 0xFFFF), d7 = (int)(p1 >> 48);
        float2 v0 = X2[(size_t)d0 * 64 + lane];
        float2 v1 = X2[(size_t)d1 * 64 + lane];
        float2 v2 = X2[(size_t)d2 * 64 + lane];
        float2 v3 = X2[(size_t)d3 * 64 + lane];
        float2 v4 = X2[(size_t)d4 * 64 + lane];
        float2 v5 = X2[(size_t)d5 * 64 + lane];
        float2 v6 = X2[(size_t)d6 * 64 + lane];
        float2 v7 = X2[(size_t)d7 * 64 + lane];
        a.x += ((v0.x + v1.x) + (v2.x + v3.x)) + ((v4.x + v5.x) + (v6.x + v7.x));
        a.y += ((v0.y + v1.y) + (v2.y + v3.y)) + ((v4.y + v5.y) + (v6.y + v7.y));
    }
    for (; i < qn; ++i) {
        int d = myq[i];
        float2 v = X2[(size_t)d * 64 + lane];
        a.x += v.x;
        a.y += v.y;
    }

    float inv = 1.0f / (float)cdeg;
    uint32_t lo = f32_to_bf16(a.x * inv);
    uint32_t hi = f32_to_bf16(a.y * inv);
    tbf[(size_t)n * 64 + lane] = lo | (hi << 16);   // t_bf[n][2*lane], [2*lane+1]
}

// ---------------------------------------------------------------
// K3 (MFMA rewrite): g_acc[j] += sum_n relu(W[j]·t[n] + b[j]).
// R10 evidence: VALU k_gemm = 40.3us, MfmaUtil 0, ~2x over its
// LDS-pipe floor. MFMA 16x16x32 bf16 (ubench 2075 TF -> 0.5us of
// matrix work); fp32 accumulate; bias+relu+sum in fp32.
// Layout: A lane l = W[j0+jj*16+(l&15)][ks*32+(l>>4)*8 ..+8]
//         B lane l = t[nb+(l&15)][ks*32+(l>>4)*8 ..+8]
// both 16B contiguous global loads -> NO LDS. D (m89-verified):
// col=lane&15 (node), row=(lane>>4)*4+reg (j offset).
// Grid 512 x 256thr: wave w owns j-quarter [64w,64w+64), block
// owns 32 nodes (2 n-tiles). All loops fully unrolled, constant
// indices (~150 VGPR, no spill; R4 lesson checked).
// ---------------------------------------------------------------
__global__ __launch_bounds__(256) void k_gemm(const uint16_t* __restrict__ Wbf,
                                              const uint16_t* __restrict__ tbf,
                                              const float* __restrict__ bg,
                                              float* __restrict__ g_accum) {
    int wid  = threadIdx.x >> 6;
    int lane = threadIdx.x & 63;
    int j0   = wid * 64;
    int n0   = blockIdx.x * 32;
    int r    = lane & 15;            // A row (j) / B col (node)
    int kb   = (lane >> 4) * 8;      // k sub-offset within 32-step

    // A-fragments: 16 x bf16x8 = 64 VGPR, persistent
    bf16x8 afrag[4][4];
#pragma unroll
    for (int jj = 0; jj < 4; ++jj)
#pragma unroll
        for (int ks = 0; ks < 4; ++ks)
            afrag[jj][ks] = *(const bf16x8*)(Wbf + (size_t)(j0 + jj * 16 + r) * F_INF + ks * 32 + kb);

    float bjv[4][4];
#pragma unroll
    for (int jj = 0; jj < 4; ++jj)
#pragma unroll
        for (int reg = 0; reg < 4; ++reg)
            bjv[jj][reg] = bg[j0 + jj * 16 + ((lane >> 4) << 2) + reg];

    float gp[4][4];
#pragma unroll
    for (int jj = 0; jj < 4; ++jj)
#pragma unroll
        for (int reg = 0; reg < 4; ++reg) gp[jj][reg] = 0.0f;

#pragma unroll
    for (int nt = 0; nt < 2; ++nt) {
        int nb = n0 + nt * 16;
        bf16x8 bfrag[4];
#pragma unroll
        for (int ks = 0; ks < 4; ++ks)
            bfrag[ks] = *(const bf16x8*)(tbf + (size_t)(nb + r) * F_INF + ks * 32 + kb);
#pragma unroll
        for (int jj = 0; jj < 4; ++jj) {
            f32x4 d = {0.0f, 0.0f, 0.0f, 0.0f};
#pragma unroll
            for (int ks = 0; ks < 4; ++ks)
                d = __builtin_amdgcn_mfma_f32_16x16x32_bf16(afrag[jj][ks], bfrag[ks], d, 0, 0, 0);
#pragma unroll
            for (int reg = 0; reg < 4; ++reg)
                gp[jj][reg] += fmaxf(d[reg] + bjv[jj][reg], 0.0f);
        }
    }

    // reduce over node-cols (lanes sharing lane>>4), then atomics
#pragma unroll
    for (int jj = 0; jj < 4; ++jj)
#pragma unroll
        for (int reg = 0; reg < 4; ++reg) {
            float s = gp[jj][reg];
            s += __shfl_xor(s, 1);
            s += __shfl_xor(s, 2);
            s += __shfl_xor(s, 4);
            s += __shfl_xor(s, 8);
            if ((lane & 15) == 0)
                atomicAdd(&g_accum[j0 + jj * 16 + ((lane >> 4) << 2) + reg], s);
        }
}

// ---------------------------------------------------------------
// K4: heads. g = g_accum/N; actor & critic MLPs; softmax; value.
// ---------------------------------------------------------------
__global__ __launch_bounds__(256) void k_heads(const float* __restrict__ g_accum,
                                               const float* __restrict__ W_a1,
                                               const float* __restrict__ b_a1,
                                               const float* __restrict__ W_a2,
                                               const float* __restrict__ b_a2,
                                               const float* __restrict__ W_c1,
                                               const float* __restrict__ b_c1,
                                               const float* __restrict__ W_c2,
                                               const float* __restrict__ b_c2,
                                               float* __restrict__ out) {
    __shared__ float gv[H_DIM];
    __shared__ float ah[128];   // actor hidden
    __shared__ float ch[128];   // critic hidden
    int tid = threadIdx.x;

    gv[tid] = g_accum[tid] * (1.0f / (float)N_NODES);
    __syncthreads();

    if (tid < 128) {
        float acc = b_a1[tid];
        const float* wr = W_a1 + tid * H_DIM;
        for (int k = 0; k < H_DIM; ++k) acc += wr[k] * gv[k];
        ah[tid] = fmaxf(acc, 0.0f);
    } else {
        int i = tid - 128;
        float acc = b_c1[i];
        const float* wr = W_c1 + i * H_DIM;
        for (int k = 0; k < H_DIM; ++k) acc += wr[k] * gv[k];
        ch[i] = fmaxf(acc, 0.0f);
    }
    __syncthreads();

    if (tid < 64) {
        float acc = b_a2[tid];
        const float* wr = W_a2 + tid * 128;
        for (int i = 0; i < 128; ++i) acc += wr[i] * ah[i];
        float m = acc;
        for (int off = 32; off; off >>= 1) m = fmaxf(m, __shfl_xor(m, off));
        float e = expf(acc - m);
        float s = e;
        for (int off = 32; off; off >>= 1) s += __shfl_xor(s, off);
        out[tid] = e / s;
    } else if (tid < 128) {
        int l = tid - 64;
        float acc = 0.0f;
        for (int i = l; i < 128; i += 64) acc += W_c2[i] * ch[i];
        for (int off = 32; off; off >>= 1) acc += __shfl_xor(acc, off);
        if (l == 0) out[A_DIM] = acc + b_c2[0];
    }
}

// ---------------------------------------------------------------
extern "C" void kernel_launch(void* const* d_in, const int* in_sizes, int n_in,
                              void* d_out, int out_size, void* d_ws, size_t ws_size,
                              hipStream_t stream) {
    const float* X    = (const float*)d_in[0];
    const int*   ei   = (const int*)d_in[1];
    const float* Wg   = (const float*)d_in[2];
    const float* bg   = (const float*)d_in[3];
    const float* W_a1 = (const float*)d_in[4];
    const float* b_a1 = (const float*)d_in[5];
    const float* W_a2 = (const float*)d_in[6];
    const float* b_a2 = (const float*)d_in[7];
    const float* W_c1 = (const float*)d_in[8];
    const float* b_c1 = (const float*)d_in[9];
    const float* W_c2 = (const float*)d_in[10];
    const float* b_c2 = (const float*)d_in[11];
    float* out = (float*)d_out;

    uint8_t*  ws     = (uint8_t*)d_ws;
    uint32_t* cnt    = (uint32_t*)(ws + CNT_OFF);
    float*    g_acc  = (float*)(ws + GACC_OFF);
    uint16_t* Wbf    = (uint16_t*)(ws + WBF_OFF);
    uint16_t* bucket = (uint16_t*)(ws + BUCKET_OFF);
    uint32_t* tbf32  = (uint32_t*)(ws + TBF_OFF);
    uint16_t* tbf16  = (uint16_t*)(ws + TBF_OFF);

    // zero counters + g_accum only (65.5KB)
    hipMemsetAsync(ws, 0, GACC_OFF + 1024, stream);

    k_wconv <<<(H_DIM * F_INF) / 256, 256, 0, stream>>>(Wg, Wbf);
    k_fill  <<<E_EDGES / 256, 256, 0, stream>>>(ei, cnt, bucket);
    k_gather<<<N_NODES / 4, 256, 0, stream>>>(X, cnt, bucket, tbf32);
    k_gemm  <<<N_NODES / 32, 256, 0, stream>>>(Wbf, tbf16, bg, g_acc);
    k_heads <<<1, 256, 0, stream>>>(g_acc, W_a1, b_a1, W_a2, b_a2,
                                    W_c1, b_c1, W_c2, b_c2, out);
}

// Round 12
// 155.948 us; speedup vs baseline: 1.3354x; 1.3354x over previous
//
#include <hip/hip_runtime.h>
#include <stdint.h>

// Problem constants (from reference)
#define N_NODES 16384
#define E_EDGES 524288
#define F_INF   128      // node feature dim
#define H_DIM   256      // hidden dim
#define A_DIM   64       // action size
#define BCAP    128      // bucket capacity per source (Poisson(32) tail ~1e-40)
#define GBLK    512      // k_gemm grid (32 nodes/block)

// ---------------- ws layout ----------------
// [0, 64KB)      : cnt uint32[16384]    (zeroed each launch)
// [64KB, +1KB)   : g_accum float[256]   (zeroed each launch)
// [80KB, +64KB)  : W_bf uint16[256][128]
// [160KB, +512KB): part float[GBLK][256] (fully written by k_gemm)
// [672KB, +4MB)  : bucket uint16[N][BCAP]
// [then, +4MB)   : t_bf uint16[N][128]
#define CNT_OFF    0
#define GACC_OFF   (64 * 1024)
#define WBF_OFF    (80 * 1024)
#define PART_OFF   (160 * 1024)
#define BUCKET_OFF (672 * 1024)
#define TBF_OFF    (BUCKET_OFF + (size_t)N_NODES * BCAP * 2)

typedef __attribute__((ext_vector_type(8))) short bf16x8;
typedef __attribute__((ext_vector_type(4))) float f32x4;

// round-to-nearest-even fp32 -> bf16 (bit pattern in low 16)
__device__ __forceinline__ uint32_t f32_to_bf16(float f) {
    uint32_t u = __float_as_uint(f);
    return (u + 0x7FFFu + ((u >> 16) & 1u)) >> 16;
}

// ---------------------------------------------------------------
// K0: W_gnn fp32 -> bf16 (32768 elems, one-shot)
// ---------------------------------------------------------------
__global__ __launch_bounds__(256) void k_wconv(const float* __restrict__ Wg,
                                               uint16_t* __restrict__ Wbf) {
    int i = blockIdx.x * 256 + threadIdx.x;
    Wbf[i] = (uint16_t)f32_to_bf16(Wg[i]);
}

// ---------------------------------------------------------------
// K1: bucketed adjacency-list build. slot=atomicAdd(cnt[s]) gives
// position and final count. Counters 64KB (L2-hot), buckets 4MB.
// (16384 counter addresses -> no same-line storm, unlike R11 gemm.)
// ---------------------------------------------------------------
__global__ __launch_bounds__(256) void k_fill(const int* __restrict__ ei,
                                              uint32_t* __restrict__ cnt,
                                              uint16_t* __restrict__ bucket) {
    int e = blockIdx.x * 256 + threadIdx.x;
    int s = ei[e];              // edge_index[0][e]
    int d = ei[E_EDGES + e];    // edge_index[1][e]
    uint32_t slot = atomicAdd(&cnt[s], 1u);
    if (slot < BCAP) bucket[(size_t)s * BCAP + slot] = (uint16_t)d;
}

// ---------------------------------------------------------------
// K2: one wave per node. LDS-bitmap set-dedup, ballot compaction,
// batched MLP=8 float2 gathers. Epilogue writes t as PACKED BF16.
// ---------------------------------------------------------------
__global__ __launch_bounds__(256) void k_gather(const float* __restrict__ X,
                                                const uint32_t* __restrict__ cnt,
                                                const uint16_t* __restrict__ bucket,
                                                uint32_t* __restrict__ tbf) {
    __shared__ uint32_t bmp[4][512];    // 16384 bits per wave
    __shared__ uint16_t q[4][BCAP];
    int wid  = threadIdx.x >> 6;
    int lane = threadIdx.x & 63;
    int n    = blockIdx.x * 4 + wid;
    uint32_t* mybm = bmp[wid];
    uint16_t* myq  = q[wid];
    const float2* X2 = (const float2*)X;

#pragma unroll
    for (int i = 0; i < 8; ++i) mybm[lane + i * 64] = 0u;

    int m = (int)cnt[n];
    if (m > BCAP) m = BCAP;
    const uint16_t* list = bucket + (size_t)n * BCAP;

    int qn = 0;
    for (int base = 0; base < m; base += 64) {
        int idx = base + lane;
        int d = 0;
        bool keep = false;
        if (idx < m) {
            d = list[idx];
            uint32_t bit = 1u << (d & 31);
            uint32_t old = atomicOr(&mybm[d >> 5], bit);
            keep = !(old & bit);
        }
        unsigned long long mask = __ballot(keep);
        int pos = qn + __popcll(mask & ((1ull << lane) - 1ull));
        if (keep) myq[pos] = (uint16_t)d;
        qn += __popcll(mask);
    }

    float2 a = X2[(size_t)n * 64 + lane];       // identity term
    int cdeg = 1 + qn;

    const uint64_t* q8 = (const uint64_t*)myq;
    int i = 0;
    for (; i + 8 <= qn; i += 8) {
        uint64_t p0 = q8[(i >> 2)];
        uint64_t p1 = q8[(i >> 2) + 1];
        int d0 = (int)(p0 & 0xFFFF), d1 = (int)((p0 >> 16) & 0xFFFF);
        int d2 = (int)((p0 >> 32) & 0xFFFF), d3 = (int)(p0 >> 48);
        int d4 = (int)(p1 & 0xFFFF), d5 = (int)((p1 >> 16) & 0xFFFF);
        int d6 = (int)((p1 >> 32) & 0xFFFF), d7 = (int)(p1 >> 48);
        float2 v0 = X2[(size_t)d0 * 64 + lane];
        float2 v1 = X2[(size_t)d1 * 64 + lane];
        float2 v2 = X2[(size_t)d2 * 64 + lane];
        float2 v3 = X2[(size_t)d3 * 64 + lane];
        float2 v4 = X2[(size_t)d4 * 64 + lane];
        float2 v5 = X2[(size_t)d5 * 64 + lane];
        float2 v6 = X2[(size_t)d6 * 64 + lane];
        float2 v7 = X2[(size_t)d7 * 64 + lane];
        a.x += ((v0.x + v1.x) + (v2.x + v3.x)) + ((v4.x + v5.x) + (v6.x + v7.x));
        a.y += ((v0.y + v1.y) + (v2.y + v3.y)) + ((v4.y + v5.y) + (v6.y + v7.y));
    }
    for (; i < qn; ++i) {
        int d = myq[i];
        float2 v = X2[(size_t)d * 64 + lane];
        a.x += v.x;
        a.y += v.y;
    }

    float inv = 1.0f / (float)cdeg;
    uint32_t lo = f32_to_bf16(a.x * inv);
    uint32_t hi = f32_to_bf16(a.y * inv);
    tbf[(size_t)n * 64 + lane] = lo | (hi << 16);   // t_bf[n][2*lane], [2*lane+1]
}

// ---------------------------------------------------------------
// K3 (MFMA): part[bid][j] = sum_{n in block} relu(W[j]·t[n]+b[j]).
// R11 evidence: math correct (absmax 1.2e-4) but the 131K global
// fp32 atomicAdds onto 16 cache lines serialized cross-XCD at the
// home L2 -> 66us with both pipes ~0% busy. *** Epilogue now does
// NON-ATOMIC stores to part[GBLK][256]; k_reduce sums them. ***
// Layout (verified): A lane l = W[j0+jj*16+(l&15)][ks*32+(l>>4)*8..]
//   B lane l = t[nb+(l&15)][same]; D col=lane&15, row=(lane>>4)*4+reg.
// ---------------------------------------------------------------
__global__ __launch_bounds__(256) void k_gemm(const uint16_t* __restrict__ Wbf,
                                              const uint16_t* __restrict__ tbf,
                                              const float* __restrict__ bg,
                                              float* __restrict__ part) {
    int wid  = threadIdx.x >> 6;
    int lane = threadIdx.x & 63;
    int j0   = wid * 64;
    int n0   = blockIdx.x * 32;
    int r    = lane & 15;            // A row (j) / B col (node)
    int kb   = (lane >> 4) * 8;      // k sub-offset within 32-step

    // A-fragments: 16 x bf16x8 = 64 VGPR, persistent
    bf16x8 afrag[4][4];
#pragma unroll
    for (int jj = 0; jj < 4; ++jj)
#pragma unroll
        for (int ks = 0; ks < 4; ++ks)
            afrag[jj][ks] = *(const bf16x8*)(Wbf + (size_t)(j0 + jj * 16 + r) * F_INF + ks * 32 + kb);

    float bjv[4][4];
#pragma unroll
    for (int jj = 0; jj < 4; ++jj)
#pragma unroll
        for (int reg = 0; reg < 4; ++reg)
            bjv[jj][reg] = bg[j0 + jj * 16 + ((lane >> 4) << 2) + reg];

    float gp[4][4];
#pragma unroll
    for (int jj = 0; jj < 4; ++jj)
#pragma unroll
        for (int reg = 0; reg < 4; ++reg) gp[jj][reg] = 0.0f;

#pragma unroll
    for (int nt = 0; nt < 2; ++nt) {
        int nb = n0 + nt * 16;
        bf16x8 bfrag[4];
#pragma unroll
        for (int ks = 0; ks < 4; ++ks)
            bfrag[ks] = *(const bf16x8*)(tbf + (size_t)(nb + r) * F_INF + ks * 32 + kb);
#pragma unroll
        for (int jj = 0; jj < 4; ++jj) {
            f32x4 d = {0.0f, 0.0f, 0.0f, 0.0f};
#pragma unroll
            for (int ks = 0; ks < 4; ++ks)
                d = __builtin_amdgcn_mfma_f32_16x16x32_bf16(afrag[jj][ks], bfrag[ks], d, 0, 0, 0);
#pragma unroll
            for (int reg = 0; reg < 4; ++reg)
                gp[jj][reg] += fmaxf(d[reg] + bjv[jj][reg], 0.0f);
        }
    }

    // reduce over the 16 node-cols, then ONE plain store per (j)
    float* prow = part + (size_t)blockIdx.x * H_DIM;
#pragma unroll
    for (int jj = 0; jj < 4; ++jj)
#pragma unroll
        for (int reg = 0; reg < 4; ++reg) {
            float s = gp[jj][reg];
            s += __shfl_xor(s, 1);
            s += __shfl_xor(s, 2);
            s += __shfl_xor(s, 4);
            s += __shfl_xor(s, 8);
            if ((lane & 15) == 0)
                prow[j0 + jj * 16 + ((lane >> 4) << 2) + reg] = s;
        }
}

// ---------------------------------------------------------------
// K3b: g_acc[j] += sum over 32 part-rows. 16 blocks -> 4096
// atomics total (16/address), coalesced loads.
// ---------------------------------------------------------------
__global__ __launch_bounds__(256) void k_reduce(const float* __restrict__ part,
                                                float* __restrict__ g_acc) {
    int j  = threadIdx.x;
    int b0 = blockIdx.x * (GBLK / 16);
    float s = 0.0f;
#pragma unroll 8
    for (int b = 0; b < GBLK / 16; ++b)
        s += part[(size_t)(b0 + b) * H_DIM + j];
    atomicAdd(&g_acc[j], s);
}

// ---------------------------------------------------------------
// K4: heads. g = g_accum/N; actor & critic MLPs; softmax; value.
// ---------------------------------------------------------------
__global__ __launch_bounds__(256) void k_heads(const float* __restrict__ g_accum,
                                               const float* __restrict__ W_a1,
                                               const float* __restrict__ b_a1,
                                               const float* __restrict__ W_a2,
                                               const float* __restrict__ b_a2,
                                               const float* __restrict__ W_c1,
                                               const float* __restrict__ b_c1,
                                               const float* __restrict__ W_c2,
                                               const float* __restrict__ b_c2,
                                               float* __restrict__ out) {
    __shared__ float gv[H_DIM];
    __shared__ float ah[128];   // actor hidden
    __shared__ float ch[128];   // critic hidden
    int tid = threadIdx.x;

    gv[tid] = g_accum[tid] * (1.0f / (float)N_NODES);
    __syncthreads();

    if (tid < 128) {
        float acc = b_a1[tid];
        const float* wr = W_a1 + tid * H_DIM;
        for (int k = 0; k < H_DIM; ++k) acc += wr[k] * gv[k];
        ah[tid] = fmaxf(acc, 0.0f);
    } else {
        int i = tid - 128;
        float acc = b_c1[i];
        const float* wr = W_c1 + i * H_DIM;
        for (int k = 0; k < H_DIM; ++k) acc += wr[k] * gv[k];
        ch[i] = fmaxf(acc, 0.0f);
    }
    __syncthreads();

    if (tid < 64) {
        float acc = b_a2[tid];
        const float* wr = W_a2 + tid * 128;
        for (int i = 0; i < 128; ++i) acc += wr[i] * ah[i];
        float m = acc;
        for (int off = 32; off; off >>= 1) m = fmaxf(m, __shfl_xor(m, off));
        float e = expf(acc - m);
        float s = e;
        for (int off = 32; off; off >>= 1) s += __shfl_xor(s, off);
        out[tid] = e / s;
    } else if (tid < 128) {
        int l = tid - 64;
        float acc = 0.0f;
        for (int i = l; i < 128; i += 64) acc += W_c2[i] * ch[i];
        for (int off = 32; off; off >>= 1) acc += __shfl_xor(acc, off);
        if (l == 0) out[A_DIM] = acc + b_c2[0];
    }
}

// ---------------------------------------------------------------
extern "C" void kernel_launch(void* const* d_in, const int* in_sizes, int n_in,
                              void* d_out, int out_size, void* d_ws, size_t ws_size,
                              hipStream_t stream) {
    const float* X    = (const float*)d_in[0];
    const int*   ei   = (const int*)d_in[1];
    const float* Wg   = (const float*)d_in[2];
    const float* bg   = (const float*)d_in[3];
    const float* W_a1 = (const float*)d_in[4];
    const float* b_a1 = (const float*)d_in[5];
    const float* W_a2 = (const float*)d_in[6];
    const float* b_a2 = (const float*)d_in[7];
    const float* W_c1 = (const float*)d_in[8];
    const float* b_c1 = (const float*)d_in[9];
    const float* W_c2 = (const float*)d_in[10];
    const float* b_c2 = (const float*)d_in[11];
    float* out = (float*)d_out;

    uint8_t*  ws     = (uint8_t*)d_ws;
    uint32_t* cnt    = (uint32_t*)(ws + CNT_OFF);
    float*    g_acc  = (float*)(ws + GACC_OFF);
    uint16_t* Wbf    = (uint16_t*)(ws + WBF_OFF);
    float*    part   = (float*)(ws + PART_OFF);
    uint16_t* bucket = (uint16_t*)(ws + BUCKET_OFF);
    uint32_t* tbf32  = (uint32_t*)(ws + TBF_OFF);
    uint16_t* tbf16  = (uint16_t*)(ws + TBF_OFF);

    // zero counters + g_accum only (65.5KB)
    hipMemsetAsync(ws, 0, GACC_OFF + 1024, stream);

    k_wconv <<<(H_DIM * F_INF) / 256, 256, 0, stream>>>(Wg, Wbf);
    k_fill  <<<E_EDGES / 256, 256, 0, stream>>>(ei, cnt, bucket);
    k_gather<<<N_NODES / 4, 256, 0, stream>>>(X, cnt, bucket, tbf32);
    k_gemm  <<<GBLK, 256, 0, stream>>>(Wbf, tbf16, bg, part);
    k_reduce<<<16, 256, 0, stream>>>(part, g_acc);
    k_heads <<<1, 256, 0, stream>>>(g_acc, W_a1, b_a1, W_a2, b_a2,
                                    W_c1, b_c1, W_c2, b_c2, out);
}

// Round 13
// 144.594 us; speedup vs baseline: 1.4403x; 1.0785x over previous
//
#include <hip/hip_runtime.h>
#include <stdint.h>

// Problem constants (from reference)
#define N_NODES 16384
#define E_EDGES 524288
#define F_INF   128      // node feature dim
#define H_DIM   256      // hidden dim
#define A_DIM   64       // action size
#define BCAP    128      // bucket capacity per source (Poisson(32) tail ~1e-40)
#define GBLK    512      // k_gemm grid (32 nodes/block)

// ---------------- ws layout ----------------
// [0, 64KB)       : cnt uint32[16384]      (zeroed by k_prep)
// [64KB, +1KB)    : g_accum float[256]     (zeroed by k_prep)
// [80KB, +64KB)   : W_bf uint16[256][128]
// [160KB, +512KB) : part float[GBLK][256]  (fully written by k_gemm)
// [672KB, +4MB)   : X_bf uint16[N][128]
// [next, +4MB)    : bucket uint16[N][BCAP]
// [next, +4MB)    : t_bf uint16[N][128]
#define CNT_OFF    0
#define GACC_OFF   (64 * 1024)
#define WBF_OFF    (80 * 1024)
#define PART_OFF   (160 * 1024)
#define XBF_OFF    (672 * 1024)
#define BUCKET_OFF (XBF_OFF + (size_t)N_NODES * F_INF * 2)
#define TBF_OFF    (BUCKET_OFF + (size_t)N_NODES * BCAP * 2)

typedef __attribute__((ext_vector_type(8))) short bf16x8;
typedef __attribute__((ext_vector_type(4))) float f32x4;

// round-to-nearest-even fp32 -> bf16 (bit pattern in low 16)
__device__ __forceinline__ uint32_t f32_to_bf16(float f) {
    uint32_t u = __float_as_uint(f);
    return (u + 0x7FFFu + ((u >> 16) & 1u)) >> 16;
}
__device__ __forceinline__ uint32_t pack_bf16(float lo, float hi) {
    return f32_to_bf16(lo) | (f32_to_bf16(hi) << 16);
}
__device__ __forceinline__ float bf_lo(uint32_t u) { return __uint_as_float(u << 16); }
__device__ __forceinline__ float bf_hi(uint32_t u) { return __uint_as_float(u & 0xFFFF0000u); }

// ---------------------------------------------------------------
// K0 (fused prep, replaces memset+wconv): zero cnt & g_acc,
// W fp32->bf16 (16K pairs), X fp32->bf16 (1M pairs). 4096 blocks.
// bf16-X rationale (R12): gather reads 524K x 512B = 268MB of
// fp32 X (8MB, doesn't fit 4MB/XCD L2). bf16 X = 4MB -> L2-
// resident, gather bytes halve to 134MB.
// ---------------------------------------------------------------
__global__ __launch_bounds__(256) void k_prep(const float* __restrict__ X,
                                              const float* __restrict__ Wg,
                                              uint32_t* __restrict__ Xbf,
                                              uint32_t* __restrict__ Wbf,
                                              uint32_t* __restrict__ cnt,
                                              float* __restrict__ g_acc) {
    int i = blockIdx.x * 256 + threadIdx.x;
    // X: 2,097,152 elems = 1,048,576 pairs
    float2 xv = ((const float2*)X)[i];
    Xbf[i] = pack_bf16(xv.x, xv.y);
    if (i < 16384) {
        float2 wv = ((const float2*)Wg)[i];   // 32768 W elems = 16384 pairs
        Wbf[i] = pack_bf16(wv.x, wv.y);
        cnt[i] = 0u;
    }
    if (i < 256) g_acc[i] = 0.0f;
}

// ---------------------------------------------------------------
// K1: bucketed adjacency-list build. slot=atomicAdd(cnt[s]) gives
// position and final count. Counters 64KB (L2-hot), buckets 4MB.
// ---------------------------------------------------------------
__global__ __launch_bounds__(256) void k_fill(const int* __restrict__ ei,
                                              uint32_t* __restrict__ cnt,
                                              uint16_t* __restrict__ bucket) {
    int e = blockIdx.x * 256 + threadIdx.x;
    int s = ei[e];              // edge_index[0][e]
    int d = ei[E_EDGES + e];    // edge_index[1][e]
    uint32_t slot = atomicAdd(&cnt[s], 1u);
    if (slot < BCAP) bucket[(size_t)s * BCAP + slot] = (uint16_t)d;
}

// ---------------------------------------------------------------
// K2: one wave per node. LDS-bitmap set-dedup, ballot compaction,
// batched MLP=8 gathers of PACKED-BF16 X rows (uint32/lane =
// 2 elems, 256B/row). fp32 accumulate; t written packed bf16.
// ---------------------------------------------------------------
__global__ __launch_bounds__(256) void k_gather(const uint32_t* __restrict__ Xbf,
                                                const uint32_t* __restrict__ cnt,
                                                const uint16_t* __restrict__ bucket,
                                                uint32_t* __restrict__ tbf) {
    __shared__ uint32_t bmp[4][512];    // 16384 bits per wave
    __shared__ uint16_t q[4][BCAP];
    int wid  = threadIdx.x >> 6;
    int lane = threadIdx.x & 63;
    int n    = blockIdx.x * 4 + wid;
    uint32_t* mybm = bmp[wid];
    uint16_t* myq  = q[wid];

#pragma unroll
    for (int i = 0; i < 8; ++i) mybm[lane + i * 64] = 0u;

    int m = (int)cnt[n];
    if (m > BCAP) m = BCAP;
    const uint16_t* list = bucket + (size_t)n * BCAP;

    int qn = 0;
    for (int base = 0; base < m; base += 64) {
        int idx = base + lane;
        int d = 0;
        bool keep = false;
        if (idx < m) {
            d = list[idx];
            uint32_t bit = 1u << (d & 31);
            uint32_t old = atomicOr(&mybm[d >> 5], bit);
            keep = !(old & bit);
        }
        unsigned long long mask = __ballot(keep);
        int pos = qn + __popcll(mask & ((1ull << lane) - 1ull));
        if (keep) myq[pos] = (uint16_t)d;
        qn += __popcll(mask);
    }

    // identity term from bf16 X (keeps fp32 X out of L2)
    uint32_t su = Xbf[(size_t)n * 64 + lane];
    float ax = bf_lo(su), ay = bf_hi(su);
    int cdeg = 1 + qn;

    const uint64_t* q8 = (const uint64_t*)myq;
    int i = 0;
    for (; i + 8 <= qn; i += 8) {
        uint64_t p0 = q8[(i >> 2)];
        uint64_t p1 = q8[(i >> 2) + 1];
        int d0 = (int)(p0 & 0xFFFF), d1 = (int)((p0 >> 16) & 0xFFFF);
        int d2 = (int)((p0 >> 32) & 0xFFFF), d3 = (int)(p0 >> 48);
        int d4 = (int)(p1 & 0xFFFF), d5 = (int)((p1 >> 16) & 0xFFFF);
        int d6 = (int)((p1 >> 32) & 0xFFFF), d7 = (int)(p1 >> 48);
        uint32_t u0 = Xbf[(size_t)d0 * 64 + lane];
        uint32_t u1 = Xbf[(size_t)d1 * 64 + lane];
        uint32_t u2 = Xbf[(size_t)d2 * 64 + lane];
        uint32_t u3 = Xbf[(size_t)d3 * 64 + lane];
        uint32_t u4 = Xbf[(size_t)d4 * 64 + lane];
        uint32_t u5 = Xbf[(size_t)d5 * 64 + lane];
        uint32_t u6 = Xbf[(size_t)d6 * 64 + lane];
        uint32_t u7 = Xbf[(size_t)d7 * 64 + lane];
        ax += ((bf_lo(u0) + bf_lo(u1)) + (bf_lo(u2) + bf_lo(u3))) +
              ((bf_lo(u4) + bf_lo(u5)) + (bf_lo(u6) + bf_lo(u7)));
        ay += ((bf_hi(u0) + bf_hi(u1)) + (bf_hi(u2) + bf_hi(u3))) +
              ((bf_hi(u4) + bf_hi(u5)) + (bf_hi(u6) + bf_hi(u7)));
    }
    for (; i < qn; ++i) {
        uint32_t u = Xbf[(size_t)myq[i] * 64 + lane];
        ax += bf_lo(u);
        ay += bf_hi(u);
    }

    float inv = 1.0f / (float)cdeg;
    tbf[(size_t)n * 64 + lane] = pack_bf16(ax * inv, ay * inv);
}

// ---------------------------------------------------------------
// K3 (MFMA): part[bid][j] = sum_{n in block} relu(W[j]·t[n]+b[j]).
// R11->R12: non-atomic stores to part + k_reduce fixed the 66us
// cross-XCD atomic storm (gemm now <top-5). Layout (verified):
// A lane l = W[j0+jj*16+(l&15)][ks*32+(l>>4)*8..], B same for t;
// D col=lane&15, row=(lane>>4)*4+reg.
// ---------------------------------------------------------------
__global__ __launch_bounds__(256) void k_gemm(const uint16_t* __restrict__ Wbf,
                                              const uint16_t* __restrict__ tbf,
                                              const float* __restrict__ bg,
                                              float* __restrict__ part) {
    int wid  = threadIdx.x >> 6;
    int lane = threadIdx.x & 63;
    int j0   = wid * 64;
    int n0   = blockIdx.x * 32;
    int r    = lane & 15;            // A row (j) / B col (node)
    int kb   = (lane >> 4) * 8;      // k sub-offset within 32-step

    bf16x8 afrag[4][4];
#pragma unroll
    for (int jj = 0; jj < 4; ++jj)
#pragma unroll
        for (int ks = 0; ks < 4; ++ks)
            afrag[jj][ks] = *(const bf16x8*)(Wbf + (size_t)(j0 + jj * 16 + r) * F_INF + ks * 32 + kb);

    float bjv[4][4];
#pragma unroll
    for (int jj = 0; jj < 4; ++jj)
#pragma unroll
        for (int reg = 0; reg < 4; ++reg)
            bjv[jj][reg] = bg[j0 + jj * 16 + ((lane >> 4) << 2) + reg];

    float gp[4][4];
#pragma unroll
    for (int jj = 0; jj < 4; ++jj)
#pragma unroll
        for (int reg = 0; reg < 4; ++reg) gp[jj][reg] = 0.0f;

#pragma unroll
    for (int nt = 0; nt < 2; ++nt) {
        int nb = n0 + nt * 16;
        bf16x8 bfrag[4];
#pragma unroll
        for (int ks = 0; ks < 4; ++ks)
            bfrag[ks] = *(const bf16x8*)(tbf + (size_t)(nb + r) * F_INF + ks * 32 + kb);
#pragma unroll
        for (int jj = 0; jj < 4; ++jj) {
            f32x4 d = {0.0f, 0.0f, 0.0f, 0.0f};
#pragma unroll
            for (int ks = 0; ks < 4; ++ks)
                d = __builtin_amdgcn_mfma_f32_16x16x32_bf16(afrag[jj][ks], bfrag[ks], d, 0, 0, 0);
#pragma unroll
            for (int reg = 0; reg < 4; ++reg)
                gp[jj][reg] += fmaxf(d[reg] + bjv[jj][reg], 0.0f);
        }
    }

    float* prow = part + (size_t)blockIdx.x * H_DIM;
#pragma unroll
    for (int jj = 0; jj < 4; ++jj)
#pragma unroll
        for (int reg = 0; reg < 4; ++reg) {
            float s = gp[jj][reg];
            s += __shfl_xor(s, 1);
            s += __shfl_xor(s, 2);
            s += __shfl_xor(s, 4);
            s += __shfl_xor(s, 8);
            if ((lane & 15) == 0)
                prow[j0 + jj * 16 + ((lane >> 4) << 2) + reg] = s;
        }
}

// ---------------------------------------------------------------
// K3b: g_acc[j] += sum over 32 part-rows. 16 blocks -> 4096
// atomics total (16/address), coalesced loads.
// ---------------------------------------------------------------
__global__ __launch_bounds__(256) void k_reduce(const float* __restrict__ part,
                                                float* __restrict__ g_acc) {
    int j  = threadIdx.x;
    int b0 = blockIdx.x * (GBLK / 16);
    float s = 0.0f;
#pragma unroll 8
    for (int b = 0; b < GBLK / 16; ++b)
        s += part[(size_t)(b0 + b) * H_DIM + j];
    atomicAdd(&g_acc[j], s);
}

// ---------------------------------------------------------------
// K4: heads. g = g_accum/N; actor & critic MLPs; softmax; value.
// ---------------------------------------------------------------
__global__ __launch_bounds__(256) void k_heads(const float* __restrict__ g_accum,
                                               const float* __restrict__ W_a1,
                                               const float* __restrict__ b_a1,
                                               const float* __restrict__ W_a2,
                                               const float* __restrict__ b_a2,
                                               const float* __restrict__ W_c1,
                                               const float* __restrict__ b_c1,
                                               const float* __restrict__ W_c2,
                                               const float* __restrict__ b_c2,
                                               float* __restrict__ out) {
    __shared__ float gv[H_DIM];
    __shared__ float ah[128];   // actor hidden
    __shared__ float ch[128];   // critic hidden
    int tid = threadIdx.x;

    gv[tid] = g_accum[tid] * (1.0f / (float)N_NODES);
    __syncthreads();

    if (tid < 128) {
        float acc = b_a1[tid];
        const float* wr = W_a1 + tid * H_DIM;
        for (int k = 0; k < H_DIM; ++k) acc += wr[k] * gv[k];
        ah[tid] = fmaxf(acc, 0.0f);
    } else {
        int i = tid - 128;
        float acc = b_c1[i];
        const float* wr = W_c1 + i * H_DIM;
        for (int k = 0; k < H_DIM; ++k) acc += wr[k] * gv[k];
        ch[i] = fmaxf(acc, 0.0f);
    }
    __syncthreads();

    if (tid < 64) {
        float acc = b_a2[tid];
        const float* wr = W_a2 + tid * 128;
        for (int i = 0; i < 128; ++i) acc += wr[i] * ah[i];
        float m = acc;
        for (int off = 32; off; off >>= 1) m = fmaxf(m, __shfl_xor(m, off));
        float e = expf(acc - m);
        float s = e;
        for (int off = 32; off; off >>= 1) s += __shfl_xor(s, off);
        out[tid] = e / s;
    } else if (tid < 128) {
        int l = tid - 64;
        float acc = 0.0f;
        for (int i = l; i < 128; i += 64) acc += W_c2[i] * ch[i];
        for (int off = 32; off; off >>= 1) acc += __shfl_xor(acc, off);
        if (l == 0) out[A_DIM] = acc + b_c2[0];
    }
}

// ---------------------------------------------------------------
extern "C" void kernel_launch(void* const* d_in, const int* in_sizes, int n_in,
                              void* d_out, int out_size, void* d_ws, size_t ws_size,
                              hipStream_t stream) {
    const float* X    = (const float*)d_in[0];
    const int*   ei   = (const int*)d_in[1];
    const float* Wg   = (const float*)d_in[2];
    const float* bg   = (const float*)d_in[3];
    const float* W_a1 = (const float*)d_in[4];
    const float* b_a1 = (const float*)d_in[5];
    const float* W_a2 = (const float*)d_in[6];
    const float* b_a2 = (const float*)d_in[7];
    const float* W_c1 = (const float*)d_in[8];
    const float* b_c1 = (const float*)d_in[9];
    const float* W_c2 = (const float*)d_in[10];
    const float* b_c2 = (const float*)d_in[11];
    float* out = (float*)d_out;

    uint8_t*  ws     = (uint8_t*)d_ws;
    uint32_t* cnt    = (uint32_t*)(ws + CNT_OFF);
    float*    g_acc  = (float*)(ws + GACC_OFF);
    uint32_t* Wbf32  = (uint32_t*)(ws + WBF_OFF);
    uint16_t* Wbf16  = (uint16_t*)(ws + WBF_OFF);
    float*    part   = (float*)(ws + PART_OFF);
    uint32_t* Xbf    = (uint32_t*)(ws + XBF_OFF);
    uint16_t* bucket = (uint16_t*)(ws + BUCKET_OFF);
    uint32_t* tbf32  = (uint32_t*)(ws + TBF_OFF);
    uint16_t* tbf16  = (uint16_t*)(ws + TBF_OFF);

    k_prep  <<<(N_NODES * F_INF / 2) / 256, 256, 0, stream>>>(X, Wg, Xbf, Wbf32, cnt, g_acc);
    k_fill  <<<E_EDGES / 256, 256, 0, stream>>>(ei, cnt, bucket);
    k_gather<<<N_NODES / 4, 256, 0, stream>>>(Xbf, cnt, bucket, tbf32);
    k_gemm  <<<GBLK, 256, 0, stream>>>(Wbf16, tbf16, bg, part);
    k_reduce<<<16, 256, 0, stream>>>(part, g_acc);
    k_heads <<<1, 256, 0, stream>>>(g_acc, W_a1, b_a1, W_a2, b_a2,
                                    W_c1, b_c1, W_c2, b_c2, out);
}